// Round 4
// baseline (8624.590 us; speedup 1.0000x reference)
//
#include <hip/hip_runtime.h>
#include <math.h>

// Soft silhouette renderer — EXACT PROBE v2 (round 4).
// verts: (4, 778, 3) f32   faces: (1538, 3) i32   out: (4, 320, 320) f32
//
// R1-R3 all failed with bit-identical absmax 0.2227 across culled/fast and
// exact/precise variants => deterministic semantic divergence in a shared
// choice. Only shared semantic choice: degenerate-face (repeated vertex
// index) sign handling. Hypothesis: the reference evaluator CONTRACTS
//   area2 = (x1-x0)*(y2-y0) - (y1-y0)*(x2-x0)
// into fma(dx1, dy2, -round(dy1*dx2)). Consequences:
//   i0==i1 / i0==i2 : a difference vector is exactly (0,0) -> area2==0 ->
//                     sign 0 -> prob = 1/8 everywhere (what we already do)
//   i1==i2          : area2 = rounding residual != 0 -> sign ±1 -> zero-area
//                     sliver. Generic edge math then yields prob =
//                     sigma(x) * 1/2 * sigma(-x): a thin ridge along the
//                     segment, INDEPENDENT of residual sign (sigma(x)sigma(-x)
//                     is even) and of fma association. So simply computing
//                     area2 with the same fma reproduces the reference field
//                     with no special-casing.
// This explains the 0.2227: our extra (7/8)^m global darkening vs the ref's
// ridge-only slivers gives max diff (7/8)^k_a*(1-(7/8)^m) ~ 0.205..0.253 for
// the expected ~6 degenerate faces split across types.
//
// Everything else identical to R3's exact probe (controlled experiment):
// no culling, no compaction, precise expf/log1pf, reference-form d.

#define IMG_S 320
#define N_FACES 1538
#define N_VERTS 778
#define TILE 16
#define CHUNK_F 256

__global__ __launch_bounds__(256)
void silhouette_exact(const float* __restrict__ verts,
                      const int* __restrict__ faces,
                      float* __restrict__ out)
{
    // SoA face cache: per edge {ax, ay, ex, ey, inv_len} + per-face sgn
    __shared__ float sAx[3][CHUNK_F];
    __shared__ float sAy[3][CHUNK_F];
    __shared__ float sEx[3][CHUNK_F];
    __shared__ float sEy[3][CHUNK_F];
    __shared__ float sIL[3][CHUNK_F];
    __shared__ float sSg[CHUNK_F];

    const int t  = threadIdx.x;
    const int b  = blockIdx.z;
    const int lx = t & 15;
    const int ly = t >> 4;
    const int gx = blockIdx.x * TILE + lx;
    const int gy = blockIdx.y * TILE + ly;

    const float px = (gx + 0.5f) / (float)IMG_S * 2.0f - 1.0f;
    const float py = (gy + 0.5f) / (float)IMG_S * 2.0f - 1.0f;

    const float* vb = verts + (size_t)b * N_VERTS * 3;

    float acc = 0.0f;

    const int nchunks = (N_FACES + CHUNK_F - 1) / CHUNK_F;
    for (int c = 0; c < nchunks; ++c) {
        const int base = c * CHUNK_F;
        const int f = base + t;
        if (f < N_FACES) {
            const int i0 = faces[f * 3 + 0];
            const int i1 = faces[f * 3 + 1];
            const int i2 = faces[f * 3 + 2];
            const float x0 = vb[i0 * 3 + 0], y0 = -vb[i0 * 3 + 1];
            const float x1 = vb[i1 * 3 + 0], y1 = -vb[i1 * 3 + 1];
            const float x2 = vb[i2 * 3 + 0], y2 = -vb[i2 * 3 + 1];

            // THE one change vs R3: fma-contracted area2 (XLA-style).
            // i0==i1 / i0==i2 still give exactly 0; i1==i2 gives the
            // rounding residual -> sign ±1 -> sliver ridge.
            const float dx1 = x1 - x0, dy1 = y1 - y0;
            const float dx2 = x2 - x0, dy2 = y2 - y0;
            const float area2 = __builtin_fmaf(dx1, dy2, -__fmul_rn(dy1, dx2));
            const float sgn = (area2 > 0.0f) ? 1.0f : ((area2 < 0.0f) ? -1.0f : 0.0f);
            sSg[t] = sgn;

            // edge 0: v0 -> v1
            {
                const float ex = x1 - x0, ey = y1 - y0;
                sAx[0][t] = x0; sAy[0][t] = y0; sEx[0][t] = ex; sEy[0][t] = ey;
                sIL[0][t] = 1.0f / (sqrtf(ex * ex + ey * ey) + 1e-8f);
            }
            // edge 1: v1 -> v2
            {
                const float ex = x2 - x1, ey = y2 - y1;
                sAx[1][t] = x1; sAy[1][t] = y1; sEx[1][t] = ex; sEy[1][t] = ey;
                sIL[1][t] = 1.0f / (sqrtf(ex * ex + ey * ey) + 1e-8f);
            }
            // edge 2: v2 -> v0
            {
                const float ex = x0 - x2, ey = y0 - y2;
                sAx[2][t] = x2; sAy[2][t] = y2; sEx[2][t] = ex; sEy[2][t] = ey;
                sIL[2][t] = 1.0f / (sqrtf(ex * ex + ey * ey) + 1e-8f);
            }
        }
        __syncthreads();

        const int n = (N_FACES - base < CHUNK_F) ? (N_FACES - base) : CHUNK_F;
        for (int j = 0; j < n; ++j) {
            const float sg = sSg[j];
            float lp = 0.0f;
            #pragma unroll
            for (int e = 0; e < 3; ++e) {
                const float t1 = py - sAy[e][j];
                const float t2 = px - sAx[e][j];
                const float d  = sEx[e][j] * t1 - sEy[e][j] * t2;
                const float x  = ((sg * d) * sIL[e][j]) * 100.0f;
                // log_sigmoid(x) = min(x,0) - log1p(exp(-|x|))
                lp += fminf(x, 0.0f) - log1pf(expf(-fabsf(x)));
            }
            float prob = expf(lp);
            prob = fminf(prob, 1.0f - 1e-6f);
            acc += log1pf(-prob);
        }
        __syncthreads();
    }

    out[(size_t)b * (IMG_S * IMG_S) + (size_t)gy * IMG_S + gx] = 1.0f - expf(acc);
}

extern "C" void kernel_launch(void* const* d_in, const int* in_sizes, int n_in,
                              void* d_out, int out_size, void* d_ws, size_t ws_size,
                              hipStream_t stream) {
    const float* verts = (const float*)d_in[0];
    const int* faces = (const int*)d_in[1];
    float* out = (float*)d_out;

    dim3 grid(IMG_S / TILE, IMG_S / TILE, 4);
    dim3 block(256);
    silhouette_exact<<<grid, block, 0, stream>>>(verts, faces, out);
}

// Round 5
// 109.981 us; speedup vs baseline: 78.4191x; 78.4191x over previous
//
#include <hip/hip_runtime.h>
#include <math.h>

// Soft silhouette renderer — optimized (round 5).
// verts: (4, 778, 3) f32   faces: (1538, 3) i32   out: (4, 320, 320) f32
//
// Verified-exact math core (R4, absmax 0.0):
//  * area2 = fma(dx1, dy2, -round(dy1*dx2))  -- matches the reference
//    evaluator's contraction. i0==i1 / i0==i2 -> exactly 0 -> sign 0 ->
//    prob=1/8 everywhere. i1==i2 -> rounding residual -> sign ±1 -> sliver
//    ridge. Generic edge code reproduces both with no special-casing
//    (zero-length edge folds to A=B=C=0 -> x=0 -> sigma=1/2).
//
// Re-introduced optimizations (error budget vs 2e-2 tolerance):
//  * per-face affine fold: x_e = A*px + B*py + C  (= d_e/sigma), ~1e-5 lp
//  * tile cull (16x16 px): skip face if max-over-tile of min-edge x < -14
//    => prob < e^-14 per face, <= 2.6e-3 total on acc
//  * LDS compaction of surviving faces
//  * per-pixel skip: far (m <= -14) or saturated (acc < -20) lanes pay only
//    6 FMA + min3
//  * block early exit once all 256 px saturated (error <= 2e-9); interior
//    pixels hit -13.8/covering-face so most tiles stop after 1-2 chunks
//  * fast math: prob = sigma(xa)*sigma(xb)*sigma(xc) via __expf + rcp,
//    acc += __logf(1-prob); ~1 ulp each, total << 1e-4

#define IMG_S 320
#define N_FACES 1538
#define N_VERTS 778
#define TILE 16
#define CHUNK_F 256
#define INV_SIGMA 100.0f
#define T_CUT 14.0f
#define ACC_CUT -20.0f

__global__ __launch_bounds__(256)
void silhouette_opt(const float* __restrict__ verts,
                    const int* __restrict__ faces,
                    float* __restrict__ out)
{
    __shared__ float4 sE0[CHUNK_F];
    __shared__ float4 sE1[CHUNK_F];
    __shared__ float4 sE2[CHUNK_F];
    __shared__ int sCount;
    __shared__ int sAlive;

    const int t  = threadIdx.x;
    const int b  = blockIdx.z;
    const int lx = t & 15;
    const int ly = t >> 4;
    const int gx = blockIdx.x * TILE + lx;
    const int gy = blockIdx.y * TILE + ly;

    const float w  = 2.0f / IMG_S;
    const float px = (gx + 0.5f) * w - 1.0f;
    const float py = (gy + 0.5f) * w - 1.0f;
    // center of this tile's 16x16 pixel-center grid, and its half-extent
    const float cx = (blockIdx.x * TILE + 8) * w - 1.0f;
    const float cy = (blockIdx.y * TILE + 8) * w - 1.0f;
    const float rr = 7.5f * w;

    const float* vb = verts + (size_t)b * N_VERTS * 3;

    float acc = 0.0f;

    const int nchunks = (N_FACES + CHUNK_F - 1) / CHUNK_F;
    for (int c = 0; c < nchunks; ++c) {
        if (t == 0) { sCount = 0; sAlive = 0; }
        __syncthreads();   // B1: resets visible (B3 ordered prior j-loop reads)

        if (acc >= ACC_CUT) sAlive = 1;   // benign same-value race

        const int fc = c * CHUNK_F + t;
        if (fc < N_FACES) {
            const int i0 = faces[fc * 3 + 0];
            const int i1 = faces[fc * 3 + 1];
            const int i2 = faces[fc * 3 + 2];
            const float x0 = vb[i0 * 3 + 0], y0 = -vb[i0 * 3 + 1];
            const float x1 = vb[i1 * 3 + 0], y1 = -vb[i1 * 3 + 1];
            const float x2 = vb[i2 * 3 + 0], y2 = -vb[i2 * 3 + 1];

            // VERIFIED-EXACT (R4): fma-contracted area2, matching the
            // reference. Do not "fix" to separately-rounded form.
            const float dx1 = x1 - x0, dy1 = y1 - y0;
            const float dx2 = x2 - x0, dy2 = y2 - y0;
            const float area2 = __builtin_fmaf(dx1, dy2, -__fmul_rn(dy1, dx2));
            const float sgn = (area2 > 0.0f) ? 1.0f : ((area2 < 0.0f) ? -1.0f : 0.0f);

            float4 e0, e1, e2;
            float mmin;
            {   // edge v0 -> v1
                const float ex = x1 - x0, ey = y1 - y0;
                const float s = sgn * INV_SIGMA / (sqrtf(ex * ex + ey * ey) + 1e-8f);
                const float A = -s * ey, B = s * ex, C = s * (ey * x0 - ex * y0);
                e0 = make_float4(A, B, C, 0.0f);
                mmin = fmaf(A, cx, fmaf(B, cy, C)) + rr * (fabsf(A) + fabsf(B));
            }
            {   // edge v1 -> v2
                const float ex = x2 - x1, ey = y2 - y1;
                const float s = sgn * INV_SIGMA / (sqrtf(ex * ex + ey * ey) + 1e-8f);
                const float A = -s * ey, B = s * ex, C = s * (ey * x1 - ex * y1);
                e1 = make_float4(A, B, C, 0.0f);
                mmin = fminf(mmin, fmaf(A, cx, fmaf(B, cy, C)) + rr * (fabsf(A) + fabsf(B)));
            }
            {   // edge v2 -> v0
                const float ex = x0 - x2, ey = y0 - y2;
                const float s = sgn * INV_SIGMA / (sqrtf(ex * ex + ey * ey) + 1e-8f);
                const float A = -s * ey, B = s * ex, C = s * (ey * x2 - ex * y2);
                e2 = make_float4(A, B, C, 0.0f);
                mmin = fminf(mmin, fmaf(A, cx, fmaf(B, cy, C)) + rr * (fabsf(A) + fabsf(B)));
            }
            if (mmin > -T_CUT) {
                const int slot = atomicAdd(&sCount, 1);
                sE0[slot] = e0;
                sE1[slot] = e1;
                sE2[slot] = e2;
            }
        }
        __syncthreads();   // B2: compaction + alive flag visible

        if (sAlive == 0) break;   // uniform: every pixel saturated

        const int n = sCount;
        for (int j = 0; j < n; ++j) {
            const float4 e0 = sE0[j];
            const float4 e1 = sE1[j];
            const float4 e2 = sE2[j];
            const float xa = fmaf(e0.x, px, fmaf(e0.y, py, e0.z));
            const float xb = fmaf(e1.x, px, fmaf(e1.y, py, e1.z));
            const float xc = fmaf(e2.x, px, fmaf(e2.y, py, e2.z));
            const float m = fminf(xa, fminf(xb, xc));
            if (m > -T_CUT && acc >= ACC_CUT) {
                const float pa = __builtin_amdgcn_rcpf(1.0f + __expf(-xa));
                const float pb = __builtin_amdgcn_rcpf(1.0f + __expf(-xb));
                const float pc = __builtin_amdgcn_rcpf(1.0f + __expf(-xc));
                float prob = pa * pb * pc;
                prob = fminf(prob, 1.0f - 1e-6f);
                acc += __logf(1.0f - prob);
            }
        }

        __syncthreads();   // B3: j-loop reads done before next iter's reset
    }

    out[(size_t)b * (IMG_S * IMG_S) + (size_t)gy * IMG_S + gx] = 1.0f - __expf(acc);
}

extern "C" void kernel_launch(void* const* d_in, const int* in_sizes, int n_in,
                              void* d_out, int out_size, void* d_ws, size_t ws_size,
                              hipStream_t stream) {
    const float* verts = (const float*)d_in[0];
    const int* faces = (const int*)d_in[1];
    float* out = (float*)d_out;

    dim3 grid(IMG_S / TILE, IMG_S / TILE, 4);
    dim3 block(256);
    silhouette_opt<<<grid, block, 0, stream>>>(verts, faces, out);
}